// Round 1
// baseline (2013.504 us; speedup 1.0000x reference)
//
#include <hip/hip_runtime.h>
#include <stdint.h>

// Problem constants
#define HID 100
#define B_TOTAL 512
#define T_IN 1000
#define NB 2
#define BLOCK 512   // 8 waves, 2 waves/EU

typedef __fp16 f16x8 __attribute__((ext_vector_type(8)));
typedef float f32x4 __attribute__((ext_vector_type(4)));

#define MF(A, B, C) __builtin_amdgcn_mfma_f32_16x16x32_f16((A), (B), (C), 0, 0, 0)
#define Z4 ((f32x4){0.f, 0.f, 0.f, 0.f})

// ---- fast activation math (R11-verified: absmax unchanged) ----
#if __has_builtin(__builtin_amdgcn_exp2f)
#define EXP2F(x) __builtin_amdgcn_exp2f(x)
#else
#define EXP2F(x) exp2f(x)
#endif
#if __has_builtin(__builtin_amdgcn_rcpf)
#define RCPF(x) __builtin_amdgcn_rcpf(x)
#else
#define RCPF(x) (1.0f / (x))
#endif
#define LOG2E 1.44269504f
__device__ __forceinline__ float sigm(float x) { return RCPF(1.0f + EXP2F(-LOG2E * x)); }
__device__ __forceinline__ float tanh_fast(float x) {
  return 1.0f - 2.0f * RCPF(EXP2F((2.0f * LOG2E) * x) + 1.0f);
}

// Gate-interleaved row permutation: frag row m (0..15) of N-tile tl (0..24)
// holds original gate row  g*100 + (4*tl + q)  with q = m>>2, g = m&3.
// => MFMA D: lane (col=batch, q=lane>>4) holds gates i,f,g,o of k=4*tl+q
//    in its 4 accumulator regs (D row = 4*(lane>>4)+reg).
__device__ __forceinline__ int jmap(int tl, int m) { return (m & 3) * 100 + 4 * tl + (m >> 2); }

// weight element fetchers over padded K layouts (0 in pad regions)
// L1 K-layout: [0..99]=h1, [100]=x, [101..127]=pad
__device__ __forceinline__ __fp16 w1e(const float* Whh1, const float* Wih1, int j, int k) {
  float v = 0.0f;
  if (k < 100) v = Whh1[j * 100 + k];
  else if (k == 100) v = Wih1[j];
  return (__fp16)v;
}
// L2 K-layout: [0..99]=h1(t), [100..111]=pad, [112..211]=h2(t-1), [212..223]=pad
__device__ __forceinline__ __fp16 w2e(const float* Wih2, const float* Whh2, int j, int k) {
  float v = 0.0f;
  if (k < 100) v = Wih2[j * 100 + k];
  else if (k >= 112 && k < 212) v = Whh2[j * 100 + (k - 112)];
  return (__fp16)v;
}

// A-operand fragment builders (A = W): lane supplies row m=lane&15 (permuted j),
// K elems (lane>>4)*8 + 0..7 within K-tile kt.
__device__ __forceinline__ f16x8 mka1(const float* Whh1, const float* Wih1, int tl, int kt, int m, int kg) {
  int j = jmap(tl, m);
  f16x8 r;
#pragma unroll
  for (int e = 0; e < 8; e++) r[e] = w1e(Whh1, Wih1, j, kt * 32 + kg * 8 + e);
  return r;
}
__device__ __forceinline__ f16x8 mka2(const float* Wih2, const float* Whh2, int tl, int kt, int m, int kg) {
  int j = jmap(tl, m);
  f16x8 r;
#pragma unroll
  for (int e = 0; e < 8; e++) r[e] = w2e(Wih2, Whh2, j, kt * 32 + kg * 8 + e);
  return r;
}

__global__ __launch_bounds__(BLOCK, 2) void lstm2_mfma(
    const float* __restrict__ input,  // [512,1000]
    const float* __restrict__ Wih1,   // [400,1]
    const float* __restrict__ Whh1,   // [400,100]
    const float* __restrict__ bih1,
    const float* __restrict__ bhh1,
    const float* __restrict__ Wih2,   // [400,100]
    const float* __restrict__ Whh2,   // [400,100]
    const float* __restrict__ bih2,
    const float* __restrict__ bhh2,
    const float* __restrict__ Wlin,   // [1,100]
    const float* __restrict__ blin,   // [1]
    const int* __restrict__ futp,
    float* __restrict__ out)          // [512, 1000+future]
{
  // parity double-buffered activation vectors (B-operand sources)
  __shared__ __align__(16) __fp16 H1X[2][NB][128];   // [0..99]=h1, [100]=x(next), pads 0
  __shared__ __align__(16) __fp16 H2s[2][NB][112];   // [0..99]=h2, [100..111]=pad 0
  __shared__ __align__(16) float  ybuf[2][NB][104];  // h2 f32 for y-dot (pads 0)
  __shared__ __align__(16) float  xrow[NB][T_IN];    // staged inputs (8 KB)
  __shared__ __align__(16) __fp16 T24[11 * 64 * 8];  // tile-24 W frags (wave 0, via LDS)
  __shared__ __align__(16) f32x4  qsc[8][32];        // per-wave gate-quad compaction scratch
  __shared__ float wls[104];                         // Wlin staged (pads 0)

  const int tid = threadIdx.x;
  const int lane = tid & 63;
  const int wv = tid >> 6;
  const int b0 = blockIdx.x * NB;
  const int F = futp[0];
  const int TT = T_IN + F;

  // ---------------- init: stage + zero ----------------
  for (int i = tid; i < NB * T_IN; i += BLOCK) {
    int b = i / T_IN, tt = i % T_IN;
    xrow[b][tt] = input[(size_t)(b0 + b) * T_IN + tt];
  }
  { uint32_t* z = (uint32_t*)H1X; if (tid < 256) z[tid] = 0u; }   // 2*2*128 f16
  { uint32_t* z = (uint32_t*)H2s; if (tid < 224) z[tid] = 0u; }   // 2*2*112 f16
  { float* z = (float*)ybuf; if (tid < 416) z[tid] = 0.0f; }      // 2*2*104 f32
  if (tid < 104) wls[tid] = (tid < HID) ? Wlin[tid] : 0.0f;

  const int n15 = lane & 15;
  const int kg = lane >> 4;         // K-chunk index 0..3
  const int bcol = lane & 1;        // batch for B-reads (cols>=2 replicate, harmless)

  // ---- act duty: lane L handles (ti=L>>3, q=(L>>1)&3, b=L&1) of this wave ----
  const int actn = (wv == 0) ? 32 : 24;               // wave0 also owns tile 24
  const bool is_act = (lane < actn);
  const int ati = lane >> 3, atq = (lane >> 1) & 3, atb = lane & 1;
  const int akg = 32 * ati + 4 * wv + atq;            // k index, bijective onto 0..99
  float c1v = 0.0f, c2v = 0.0f;
  f32x4 b1q = Z4, b2q = Z4;
  if (is_act) {
#pragma unroll
    for (int g = 0; g < 4; g++) {
      b1q[g] = bih1[g * 100 + akg] + bhh1[g * 100 + akg];
      b2q[g] = bih2[g * 100 + akg] + bhh2[g * 100 + akg];
    }
  }

  // ---- y duty: wave 7 lanes 48..63 ----
  const int is_y = (tid >= 496);
  const int ybat = ((tid - 496) >> 3) & 1;
  const int yl = (tid - 496) & 7;
  const float blin0 = blin[0];

  // ---- register-resident weight fragments (A-operand), tiles {wv, 8+wv, 16+wv} ----
  f16x8 W1f0[4], W1f1[4], W1f2[4], W2f0[7], W2f1[7], W2f2[7];
#pragma unroll
  for (int kt = 0; kt < 4; kt++) {
    W1f0[kt] = mka1(Whh1, Wih1, wv, kt, n15, kg);
    W1f1[kt] = mka1(Whh1, Wih1, 8 + wv, kt, n15, kg);
    W1f2[kt] = mka1(Whh1, Wih1, 16 + wv, kt, n15, kg);
  }
#pragma unroll
  for (int kt = 0; kt < 7; kt++) {
    W2f0[kt] = mka2(Wih2, Whh2, wv, kt, n15, kg);
    W2f1[kt] = mka2(Wih2, Whh2, 8 + wv, kt, n15, kg);
    W2f2[kt] = mka2(Wih2, Whh2, 16 + wv, kt, n15, kg);
  }
  // tile 24 fragments -> LDS (slots: 0..3 W1 kt0..3, 4..6 W2 kt4..6, 7..10 W2 kt0..3)
  if (tid < 64) {
    f16x8* TV = (f16x8*)T24;
    const int m_ = tid & 15, kg_ = tid >> 4;
#pragma unroll
    for (int kt = 0; kt < 4; kt++) TV[kt * 64 + tid] = mka1(Whh1, Wih1, 24, kt, m_, kg_);
#pragma unroll
    for (int kt = 0; kt < 3; kt++) TV[(4 + kt) * 64 + tid] = mka2(Wih2, Whh2, 24, 4 + kt, m_, kg_);
#pragma unroll
    for (int kt = 0; kt < 4; kt++) TV[(7 + kt) * 64 + tid] = mka2(Wih2, Whh2, 24, kt, m_, kg_);
  }

  __syncthreads();
  if (tid >= 80 && tid < 82) H1X[0][tid - 80][100] = (__fp16)xrow[tid - 80][0];  // x(0)
  __syncthreads();

  f16x8 bL1[4], bH2[3], bL2[4];

// ---- B-operand reads: lane reads its 8 contiguous K-elems for batch bcol ----
#define RD_L1(P) { _Pragma("unroll") for (int kt_ = 0; kt_ < 4; kt_++) \
    bL1[kt_] = *(const f16x8*)&H1X[P][bcol][kt_ * 32 + kg * 8]; }
#define RD_H2P(P) { _Pragma("unroll") for (int kt_ = 0; kt_ < 3; kt_++) \
    bH2[kt_] = *(const f16x8*)&H2s[P][bcol][16 + kt_ * 32 + kg * 8]; }
#define RD_L2(PH1, PH2) { _Pragma("unroll") for (int kt_ = 0; kt_ < 4; kt_++) { \
    const int k0_ = kt_ * 32 + kg * 8; \
    const __fp16* sp_ = (k0_ < 112) ? &H1X[PH1][bcol][k0_] : &H2s[PH2][bcol][k0_ - 112]; \
    bL2[kt_] = *(const f16x8*)sp_; } }

// G1: L1 gates over bL1  +  W2-tail partials over h2(t-1) (bH2)
#define PHASE1 \
  f32x4 c0 = Z4, c1 = Z4, c2 = Z4, p0 = Z4, p1 = Z4, p2 = Z4, c3 = Z4, p24 = Z4; \
  { _Pragma("unroll") for (int kt_ = 0; kt_ < 4; kt_++) { \
      c0 = MF(W1f0[kt_], bL1[kt_], c0); c1 = MF(W1f1[kt_], bL1[kt_], c1); c2 = MF(W1f2[kt_], bL1[kt_], c2); } \
    _Pragma("unroll") for (int kt_ = 0; kt_ < 3; kt_++) { \
      p0 = MF(W2f0[kt_ + 4], bH2[kt_], p0); p1 = MF(W2f1[kt_ + 4], bH2[kt_], p1); p2 = MF(W2f2[kt_ + 4], bH2[kt_], p2); } \
    if (wv == 0) { const f16x8* TV = (const f16x8*)T24; \
      _Pragma("unroll") for (int kt_ = 0; kt_ < 4; kt_++) c3 = MF(TV[kt_ * 64 + lane], bL1[kt_], c3); \
      _Pragma("unroll") for (int kt_ = 0; kt_ < 3; kt_++) p24 = MF(TV[(4 + kt_) * 64 + lane], bH2[kt_], p24); } }

// G2: W2 head over bL2 (h1(t) + h2(t-1) head), C-init = held partials
#define PHASE2 \
  f32x4 d0 = p0, d1 = p1, d2 = p2, d24 = p24; \
  { _Pragma("unroll") for (int kt_ = 0; kt_ < 4; kt_++) { \
      d0 = MF(W2f0[kt_], bL2[kt_], d0); d1 = MF(W2f1[kt_], bL2[kt_], d1); d2 = MF(W2f2[kt_], bL2[kt_], d2); } \
    if (wv == 0) { const f16x8* TV = (const f16x8*)T24; \
      _Pragma("unroll") for (int kt_ = 0; kt_ < 4; kt_++) d24 = MF(TV[(7 + kt_) * 64 + lane], bL2[kt_], d24); } }

// wave-private quad compaction: 8 useful lanes/tile -> qsc, then 1 act pass.
// same-wave ds ordering: LDS ops complete in issue order within a wave; no barrier.
#define QW1 { if ((lane & 15) < 2) { const int qi_ = (lane >> 4) * 2 + (lane & 1); \
    qsc[wv][qi_] = c0; qsc[wv][8 + qi_] = c1; qsc[wv][16 + qi_] = c2; \
    if (wv == 0) qsc[0][24 + qi_] = c3; } }
#define QW2 { if ((lane & 15) < 2) { const int qi_ = (lane >> 4) * 2 + (lane & 1); \
    qsc[wv][qi_] = d0; qsc[wv][8 + qi_] = d1; qsc[wv][16 + qi_] = d2; \
    if (wv == 0) qsc[0][24 + qi_] = d24; } }

#define ACT1 { if (is_act) { \
    f32x4 qq = qsc[wv][lane]; \
    float gi = qq[0] + b1q[0], gf = qq[1] + b1q[1], gg = qq[2] + b1q[2], go = qq[3] + b1q[3]; \
    c1v = sigm(gf) * c1v + sigm(gi) * tanh_fast(gg); \
    float h_ = sigm(go) * tanh_fast(c1v); \
    H1X[wr][atb][akg] = (__fp16)h_; } }

#define ACT2 { if (is_act) { \
    f32x4 qq = qsc[wv][lane]; \
    float gi = qq[0] + b2q[0], gf = qq[1] + b2q[1], gg = qq[2] + b2q[2], go = qq[3] + b2q[3]; \
    c2v = sigm(gf) * c2v + sigm(gi) * tanh_fast(gg); \
    float hv_ = sigm(go) * tanh_fast(c2v); \
    H2s[wr][atb][akg] = (__fp16)hv_; \
    ybuf[wr][atb][akg] = hv_; } }

#define Y_BODY(tt, PR, FEED) { \
    const float* yb_ = &ybuf[PR][ybat][0]; \
    float s = 0.0f; \
    _Pragma("unroll") \
    for (int m = 0; m < 13; m++) s = fmaf(yb_[yl + 8 * m], wls[yl + 8 * m], s); \
    s += __shfl_down(s, 4, 8); \
    s += __shfl_down(s, 2, 8); \
    s += __shfl_down(s, 1, 8); \
    if (yl == 0) { \
      float y = s + blin0; \
      out[(size_t)(b0 + ybat) * TT + (tt)] = y; \
      if (FEED) H1X[PR][ybat][100] = (__fp16)y; } }

  // initial operands: h1(-1)=0, x(0); h2(-1)=0
  RD_L1(0)
  RD_H2P(0)

  // ================= teacher-forced: 2 barriers/step =================
  for (int t = 0; t < T_IN; t++) {
    const int pr = t & 1, wr = pr ^ 1;
    PHASE1
    if (is_y && t > 0) Y_BODY(t - 1, pr, 0)           // y(t-1) off critical path
    if (tid >= 80 && tid < 82 && t + 1 < T_IN)
      H1X[wr][tid - 80][100] = (__fp16)xrow[tid - 80][t + 1];
    QW1 ACT1
    __syncthreads();                                  // B1: h1(t) + x(t+1) visible
    RD_L2(wr, pr)
    RD_L1(wr)                                         // prefetch next step's L1 operand
    PHASE2
    QW2 ACT2
    __syncthreads();                                  // B2: h2(t) + ybuf visible
    RD_H2P(wr)                                        // prefetch next step's h2 operand
  }

  // ================= autoregressive: 3 barriers/step =================
  for (int t = T_IN; t < TT; t++) {
    const int pr = t & 1, wr = pr ^ 1;
    if (is_y) Y_BODY(t - 1, pr, 1)                    // y(t-1) -> out + x(t) feed
    RD_H2P(pr)                                        // h2(t-1)
    __syncthreads();                                  // B3: y-feed visible
    RD_L1(pr)                                         // h1(t-1) + x(t)=y(t-1)
    PHASE1
    QW1 ACT1
    __syncthreads();                                  // B1
    RD_L2(wr, pr)
    PHASE2
    QW2 ACT2
    __syncthreads();                                  // B2
  }
  if (is_y) Y_BODY(TT - 1, TT & 1, 0)                 // final y
}

extern "C" void kernel_launch(void* const* d_in, const int* in_sizes, int n_in,
                              void* d_out, int out_size, void* d_ws, size_t ws_size,
                              hipStream_t stream) {
  const float* input = (const float*)d_in[0];
  const float* Wih1  = (const float*)d_in[1];
  const float* Whh1  = (const float*)d_in[2];
  const float* bih1  = (const float*)d_in[3];
  const float* bhh1  = (const float*)d_in[4];
  const float* Wih2  = (const float*)d_in[5];
  const float* Whh2  = (const float*)d_in[6];
  const float* bih2  = (const float*)d_in[7];
  const float* bhh2  = (const float*)d_in[8];
  const float* Wlin  = (const float*)d_in[9];
  const float* blin  = (const float*)d_in[10];
  const int*   futp  = (const int*)d_in[11];
  float* out = (float*)d_out;

  dim3 grid(B_TOTAL / NB);  // 256 blocks, 1 per CU
  dim3 block(BLOCK);
  hipLaunchKernelGGL(lstm2_mfma, grid, block, 0, stream,
                     input, Wih1, Whh1, bih1, bhh1, Wih2, Whh2, bih2, bhh2,
                     Wlin, blin, futp, out);
}

// Round 2
// 1659.723 us; speedup vs baseline: 1.2132x; 1.2132x over previous
//
#include <hip/hip_runtime.h>
#include <stdint.h>

// Problem constants
#define HID 100
#define B_TOTAL 512
#define T_IN 1000
#define NB 2
#define BLOCK 512   // 8 waves, 2 waves/EU

typedef __fp16 f16x8 __attribute__((ext_vector_type(8)));
typedef float f32x4 __attribute__((ext_vector_type(4)));

#define MF(A, B, C) __builtin_amdgcn_mfma_f32_16x16x32_f16((A), (B), (C), 0, 0, 0)
#define Z4 ((f32x4){0.f, 0.f, 0.f, 0.f})

// ---- fast activation math (verified: absmax unchanged) ----
#if __has_builtin(__builtin_amdgcn_exp2f)
#define EXP2F(x) __builtin_amdgcn_exp2f(x)
#else
#define EXP2F(x) exp2f(x)
#endif
#if __has_builtin(__builtin_amdgcn_rcpf)
#define RCPF(x) __builtin_amdgcn_rcpf(x)
#else
#define RCPF(x) (1.0f / (x))
#endif
#define LOG2E 1.44269504f
__device__ __forceinline__ float sigm(float x) { return RCPF(1.0f + EXP2F(-LOG2E * x)); }
__device__ __forceinline__ float tanh_fast(float x) {
  return 1.0f - 2.0f * RCPF(EXP2F((2.0f * LOG2E) * x) + 1.0f);
}

// Gate-interleaved row permutation (R1-verified): frag row m of N-tile tl holds
// original gate row g*100 + (4*tl + q), g = m&3, q = m>>2.
// => D: lane holds gates (i,f,g,o) of k=4*tl+(lane>>4), batch (lane&15)&1 in regs 0..3.
__device__ __forceinline__ int jmap(int tl, int m) { return (m & 3) * 100 + 4 * tl + (m >> 2); }

// weight element fetchers over padded K layouts (0 in pad regions).
// Bias fused at K=101 (hi) / 102 (lo) against B=1.0 — f32-exact via hi/lo f16 pair.
// L1 K-layout: [0..99]=h1, [100]=x, [101]=b_hi, [102]=b_lo, [103..127]=0
__device__ __forceinline__ __fp16 w1e(const float* Whh1, const float* Wih1,
                                      const float* bih1, const float* bhh1, int j, int k) {
  if (k < 100) return (__fp16)Whh1[j * 100 + k];
  if (k == 100) return (__fp16)Wih1[j];
  if (k == 101 || k == 102) {
    float b = bih1[j] + bhh1[j];
    __fp16 hi = (__fp16)b;
    return (k == 101) ? hi : (__fp16)(b - (float)hi);
  }
  return (__fp16)0.0f;
}
// L2 K-layout: [0..99]=h1(t), [100]=0(x-slot junk), [101]=b_hi, [102]=b_lo,
//              [103..111]=0, [112..211]=h2(t-1), [212..223]=0
__device__ __forceinline__ __fp16 w2e(const float* Wih2, const float* Whh2,
                                      const float* bih2, const float* bhh2, int j, int k) {
  if (k < 100) return (__fp16)Wih2[j * 100 + k];
  if (k == 101 || k == 102) {
    float b = bih2[j] + bhh2[j];
    __fp16 hi = (__fp16)b;
    return (k == 101) ? hi : (__fp16)(b - (float)hi);
  }
  if (k >= 112 && k < 212) return (__fp16)Whh2[j * 100 + (k - 112)];
  return (__fp16)0.0f;
}

// A-operand fragment builders: lane row m=lane&15, K elems (lane>>4)*8+0..7 of K-tile kt
__device__ __forceinline__ f16x8 mka1(const float* Whh1, const float* Wih1,
                                      const float* bih1, const float* bhh1,
                                      int tl, int kt, int m, int kg) {
  int j = jmap(tl, m);
  f16x8 r;
#pragma unroll
  for (int e = 0; e < 8; e++) r[e] = w1e(Whh1, Wih1, bih1, bhh1, j, kt * 32 + kg * 8 + e);
  return r;
}
__device__ __forceinline__ f16x8 mka2(const float* Wih2, const float* Whh2,
                                      const float* bih2, const float* bhh2,
                                      int tl, int kt, int m, int kg) {
  int j = jmap(tl, m);
  f16x8 r;
#pragma unroll
  for (int e = 0; e < 8; e++) r[e] = w2e(Wih2, Whh2, bih2, bhh2, j, kt * 32 + kg * 8 + e);
  return r;
}

__global__ __launch_bounds__(BLOCK, 2) void lstm2_mfma(
    const float* __restrict__ input,  // [512,1000]
    const float* __restrict__ Wih1,   // [400,1]
    const float* __restrict__ Whh1,   // [400,100]
    const float* __restrict__ bih1,
    const float* __restrict__ bhh1,
    const float* __restrict__ Wih2,   // [400,100]
    const float* __restrict__ Whh2,   // [400,100]
    const float* __restrict__ bih2,
    const float* __restrict__ bhh2,
    const float* __restrict__ Wlin,   // [1,100]
    const float* __restrict__ blin,   // [1]
    const int* __restrict__ futp,
    float* __restrict__ out)          // [512, 1000+future]
{
  // parity double-buffered activation vectors (B-operand sources)
  __shared__ __align__(16) __fp16 H1X[2][NB][128];   // h1 | x@100 | 1.0@101,102 | 0
  __shared__ __align__(16) __fp16 H2s[2][NB][112];   // h2 | 0 pads
  __shared__ __align__(16) float  ybuf[2][NB][104];  // h2 f32 for y-dot (pads 0)
  __shared__ __align__(16) float  xrow[NB][T_IN];    // staged inputs (8 KB)
  __shared__ __align__(16) __fp16 T24[11 * 64 * 8];  // tile-24 W frags (waves 0/1, via LDS)
  __shared__ float wls[104];                         // Wlin staged (pads 0)

  const int tid = threadIdx.x;
  const int lane = tid & 63;
  const int wv = tid >> 6;
  const int b0 = blockIdx.x * NB;
  const int F = futp[0];
  const int TT = T_IN + F;

  // ---------------- init: stage + zero ----------------
  for (int i = tid; i < NB * T_IN; i += BLOCK) {
    int b = i / T_IN, tt = i % T_IN;
    xrow[b][tt] = input[(size_t)(b0 + b) * T_IN + tt];
  }
  { uint32_t* z = (uint32_t*)H1X; if (tid < 256) z[tid] = 0u; }   // 2*2*128 f16
  { uint32_t* z = (uint32_t*)H2s; if (tid < 224) z[tid] = 0u; }   // 2*2*112 f16
  { float* z = (float*)ybuf; if (tid < 416) z[tid] = 0.0f; }      // 2*2*104 f32
  if (tid < 104) wls[tid] = (tid < HID) ? Wlin[tid] : 0.0f;

  const int n15 = lane & 15;
  const int kg = lane >> 4;         // K-chunk index 0..3
  const int bcol = lane & 1;        // batch for B-reads (cols replicate batch by parity)

  // ---- act geometry: lane activates ONE of its accumulator quads ----
  const int sel = lane & 15;
  const int cg  = sel >> 1;                       // col-group: 0..7 (0..2 valid, 3 on wv0/1)
  const int ab  = sel & 1;                        // batch
  const int aq  = lane >> 4;                      // q 0..3
  const int atl = (cg == 0) ? wv : (cg == 1) ? 8 + wv : (cg == 2) ? 16 + wv : 24;
  const int ak  = atl * 4 + aq;                   // k index this lane owns
  const bool awr1 = (sel < 6) || (wv == 0 && sel < 8);   // L1 writers (wave0 owns tile 24)
  const bool awr2 = (sel < 6) || (wv == 1 && sel < 8);   // L2 writers (wave1 owns tile 24)
  float c1v = 0.0f, c2v = 0.0f;                   // per-lane cell states

  // ---- y duty: wave 7 lanes 48..63 ----
  const int is_y = (tid >= 496);
  const int ybat = ((tid - 496) >> 3) & 1;
  const int yl = (tid - 496) & 7;
  const float blin0 = blin[0];

  // ---- register-resident weight fragments (A-operand), tiles {wv, 8+wv, 16+wv} ----
  f16x8 W1f0[4], W1f1[4], W1f2[4], W2f0[7], W2f1[7], W2f2[7];
#pragma unroll
  for (int kt = 0; kt < 4; kt++) {
    W1f0[kt] = mka1(Whh1, Wih1, bih1, bhh1, wv, kt, n15, kg);
    W1f1[kt] = mka1(Whh1, Wih1, bih1, bhh1, 8 + wv, kt, n15, kg);
    W1f2[kt] = mka1(Whh1, Wih1, bih1, bhh1, 16 + wv, kt, n15, kg);
  }
#pragma unroll
  for (int kt = 0; kt < 7; kt++) {
    W2f0[kt] = mka2(Wih2, Whh2, bih2, bhh2, wv, kt, n15, kg);
    W2f1[kt] = mka2(Wih2, Whh2, bih2, bhh2, 8 + wv, kt, n15, kg);
    W2f2[kt] = mka2(Wih2, Whh2, bih2, bhh2, 16 + wv, kt, n15, kg);
  }
  // tile 24 fragments -> LDS (slots: 0..3 W1 kt0..3, 4..6 W2 kt4..6, 7..10 W2 kt0..3)
  if (tid < 64) {
    f16x8* TV = (f16x8*)T24;
    const int m_ = tid & 15, kg_ = tid >> 4;
#pragma unroll
    for (int kt = 0; kt < 4; kt++) TV[kt * 64 + tid] = mka1(Whh1, Wih1, bih1, bhh1, 24, kt, m_, kg_);
#pragma unroll
    for (int kt = 0; kt < 3; kt++) TV[(4 + kt) * 64 + tid] = mka2(Wih2, Whh2, bih2, bhh2, 24, 4 + kt, m_, kg_);
#pragma unroll
    for (int kt = 0; kt < 4; kt++) TV[(7 + kt) * 64 + tid] = mka2(Wih2, Whh2, bih2, bhh2, 24, kt, m_, kg_);
  }

  __syncthreads();
  // specials: bias-ones at K=101,102 (both parities, both batches); x(0) into parity 1
  if (tid < 4) { H1X[tid >> 1][tid & 1][101] = (__fp16)1.0f; H1X[tid >> 1][tid & 1][102] = (__fp16)1.0f; }
  if (tid >= 4 && tid < 6) H1X[1][tid - 4][100] = (__fp16)xrow[tid - 4][0];
  __syncthreads();

  f16x8 bL1[4], bH2[3], bL2[4];
  f32x4 c0, c1, c2, c3, d0, d1, d2, d3;

// ---- B-operand reads: lane reads its 8 contiguous K-elems for batch bcol ----
#define RD_L1(P) { _Pragma("unroll") for (int kt_ = 0; kt_ < 4; kt_++) \
    bL1[kt_] = *(const f16x8*)&H1X[P][bcol][kt_ * 32 + kg * 8]; }
#define RD_H2P(P) { _Pragma("unroll") for (int kt_ = 0; kt_ < 3; kt_++) \
    bH2[kt_] = *(const f16x8*)&H2s[P][bcol][16 + kt_ * 32 + kg * 8]; }
#define RD_L2(PH1, PH2) { _Pragma("unroll") for (int kt_ = 0; kt_ < 4; kt_++) { \
    const int k0_ = kt_ * 32 + kg * 8; \
    const __fp16* sp_ = (k0_ < 112) ? &H1X[PH1][bcol][k0_] : &H2s[PH2][bcol][k0_ - 112]; \
    bL2[kt_] = *(const f16x8*)sp_; } }

// ---- MFMA bursts (bias arrives via K=101/102) ----
#define MFMA_L1 { \
    c0 = Z4; c1 = Z4; c2 = Z4; c3 = Z4; \
    _Pragma("unroll") for (int kt_ = 0; kt_ < 4; kt_++) { \
      c0 = MF(W1f0[kt_], bL1[kt_], c0); c1 = MF(W1f1[kt_], bL1[kt_], c1); c2 = MF(W1f2[kt_], bL1[kt_], c2); } \
    if (wv == 0) { const f16x8* TV = (const f16x8*)T24; \
      _Pragma("unroll") for (int kt_ = 0; kt_ < 4; kt_++) c3 = MF(TV[kt_ * 64 + lane], bL1[kt_], c3); } }

#define MFMA_L2 { \
    d0 = Z4; d1 = Z4; d2 = Z4; d3 = Z4; \
    _Pragma("unroll") for (int kt_ = 0; kt_ < 4; kt_++) { \
      d0 = MF(W2f0[kt_], bL2[kt_], d0); d1 = MF(W2f1[kt_], bL2[kt_], d1); d2 = MF(W2f2[kt_], bL2[kt_], d2); } \
    _Pragma("unroll") for (int kt_ = 0; kt_ < 3; kt_++) { \
      d0 = MF(W2f0[kt_ + 4], bH2[kt_], d0); d1 = MF(W2f1[kt_ + 4], bH2[kt_], d1); d2 = MF(W2f2[kt_ + 4], bH2[kt_], d2); } \
    if (wv == 1) { const f16x8* TV = (const f16x8*)T24; \
      _Pragma("unroll") for (int kt_ = 0; kt_ < 4; kt_++) d3 = MF(TV[(7 + kt_) * 64 + lane], bL2[kt_], d3); \
      _Pragma("unroll") for (int kt_ = 0; kt_ < 3; kt_++) d3 = MF(TV[(4 + kt_) * 64 + lane], bH2[kt_], d3); } }

// ---- in-register activations: select quad by cg, one 10-trans pass per layer ----
#define ACT1(W_) { \
    f32x4 qq = (cg == 0) ? c0 : (cg == 1) ? c1 : (cg == 2) ? c2 : c3; \
    float sf_ = sigm(qq[1]), si_ = sigm(qq[0]), tg_ = tanh_fast(qq[2]); \
    c1v = sf_ * c1v + si_ * tg_; \
    float h_ = sigm(qq[3]) * tanh_fast(c1v); \
    if (awr1) H1X[W_][ab][ak] = (__fp16)h_; }

#define ACT2(W_) { \
    f32x4 qq = (cg == 0) ? d0 : (cg == 1) ? d1 : (cg == 2) ? d2 : d3; \
    float sf_ = sigm(qq[1]), si_ = sigm(qq[0]), tg_ = tanh_fast(qq[2]); \
    c2v = sf_ * c2v + si_ * tg_; \
    float h_ = sigm(qq[3]) * tanh_fast(c2v); \
    if (awr2) { H2s[W_][ab][ak] = (__fp16)h_; ybuf[W_][ab][ak] = h_; } }

#define Y_BODY(tt, RP, FEED, FP) { \
    const float* yb_ = &ybuf[RP][ybat][0]; \
    float s = 0.0f; \
    _Pragma("unroll") \
    for (int m = 0; m < 13; m++) s = fmaf(yb_[yl + 8 * m], wls[yl + 8 * m], s); \
    s += __shfl_down(s, 4, 8); \
    s += __shfl_down(s, 2, 8); \
    s += __shfl_down(s, 1, 8); \
    if (yl == 0) { \
      float y = s + blin0; \
      out[(size_t)(b0 + ybat) * TT + (tt)] = y; \
      if (FEED) H1X[FP][ybat][100] = (__fp16)y; } }

  // ---------------- prologue: L1 gates(0) from parity 1 (zeros + x(0)) ----------------
  RD_L1(1)
  MFMA_L1
  ACT1(0)                                              // h1(0) -> H1X[0]
  if (tid >= 80 && tid < 82) H1X[0][tid - 80][100] = (__fp16)xrow[tid - 80][1];  // x(1)
  __syncthreads();

  // ====== teacher-forced fused: iter t does L2(t) + L1(t+1); ONE barrier/step ======
  for (int t = 0; t < T_IN - 1; t++) {
    const int p = t & 1, w = p ^ 1;
    RD_L1(p) RD_L2(p, p) RD_H2P(p)
    MFMA_L2
    MFMA_L1
    if (is_y && t > 0) Y_BODY(t - 1, p, 0, 0)          // y(t-1) off critical path
    if (tid >= 80 && tid < 82 && t + 2 < T_IN)
      H1X[w][tid - 80][100] = (__fp16)xrow[tid - 80][t + 2];  // x(t+2)
    ACT2(w)                                            // h2(t)
    ACT1(w)                                            // h1(t+1)
    __syncthreads();
  }

  // ====== autoregressive (incl. L2(999) entry step): 3 barriers/step ======
  for (int t = T_IN - 1; t < TT; t++) {
    const int P = t & 1, W = P ^ 1;
    RD_L2(P, P) RD_H2P(P)
    MFMA_L2
    if (is_y && t == T_IN - 1) Y_BODY(t - 1, P, 0, 0)  // catch-up y(998)
    ACT2(W)                                            // h2(t)
    __syncthreads();
    if (is_y) Y_BODY(t, W, (t + 1) < TT, P)            // y(t) -> out + x(t+1) feed
    if (t + 1 >= TT) break;
    __syncthreads();
    RD_L1(P)
    MFMA_L1
    ACT1(W)                                            // h1(t+1)
    __syncthreads();
  }
}

extern "C" void kernel_launch(void* const* d_in, const int* in_sizes, int n_in,
                              void* d_out, int out_size, void* d_ws, size_t ws_size,
                              hipStream_t stream) {
  const float* input = (const float*)d_in[0];
  const float* Wih1  = (const float*)d_in[1];
  const float* Whh1  = (const float*)d_in[2];
  const float* bih1  = (const float*)d_in[3];
  const float* bhh1  = (const float*)d_in[4];
  const float* Wih2  = (const float*)d_in[5];
  const float* Whh2  = (const float*)d_in[6];
  const float* bih2  = (const float*)d_in[7];
  const float* bhh2  = (const float*)d_in[8];
  const float* Wlin  = (const float*)d_in[9];
  const float* blin  = (const float*)d_in[10];
  const int*   futp  = (const int*)d_in[11];
  float* out = (float*)d_out;

  dim3 grid(B_TOTAL / NB);  // 256 blocks, 1 per CU
  dim3 block(BLOCK);
  hipLaunchKernelGGL(lstm2_mfma, grid, block, 0, stream,
                     input, Wih1, Whh1, bih1, bhh1, Wih2, Whh2, bih2, bhh2,
                     Wlin, blin, futp, out);
}

// Round 4
// 1575.914 us; speedup vs baseline: 1.2777x; 1.0532x over previous
//
#include <hip/hip_runtime.h>
#include <stdint.h>

// Problem constants
#define HID 100
#define B_TOTAL 512
#define T_IN 1000
#define NB 2
#define BLOCK 512   // 8 waves, 2 waves/EU
#define RSTR 160    // f16 row stride (320 B): bcol=1 lands 16 banks away -> all 32 banks used

typedef __fp16 f16x8 __attribute__((ext_vector_type(8)));
typedef __fp16 f16x2 __attribute__((ext_vector_type(2)));
typedef float f32x4 __attribute__((ext_vector_type(4)));

#define MF(A, B, C) __builtin_amdgcn_mfma_f32_16x16x32_f16((A), (B), (C), 0, 0, 0)
#define Z4 ((f32x4){0.f, 0.f, 0.f, 0.f})

// ---- fast activation math (verified: absmax unchanged) ----
#if __has_builtin(__builtin_amdgcn_exp2f)
#define EXP2F(x) __builtin_amdgcn_exp2f(x)
#else
#define EXP2F(x) exp2f(x)
#endif
#if __has_builtin(__builtin_amdgcn_rcpf)
#define RCPF(x) __builtin_amdgcn_rcpf(x)
#else
#define RCPF(x) (1.0f / (x))
#endif
#define LOG2E 1.44269504f
__device__ __forceinline__ float sigm(float x) { return RCPF(1.0f + EXP2F(-LOG2E * x)); }
__device__ __forceinline__ float tanh_fast(float x) {
  return 1.0f - 2.0f * RCPF(EXP2F((2.0f * LOG2E) * x) + 1.0f);
}

// 8-wide f16 dot accumulating into f32 (v_dot2_f32_f16 when available)
__device__ __forceinline__ float dot8(f16x8 a, f16x8 b, float acc) {
#if __has_builtin(__builtin_amdgcn_fdot2)
#pragma unroll
  for (int q = 0; q < 4; q++) {
    f16x2 xa = {a[2 * q], a[2 * q + 1]};
    f16x2 xb = {b[2 * q], b[2 * q + 1]};
    acc = __builtin_amdgcn_fdot2(xa, xb, acc, false);
  }
#else
#pragma unroll
  for (int e = 0; e < 8; e++) acc = fmaf((float)a[e], (float)b[e], acc);
#endif
  return acc;
}

// Gate-interleaved row permutation (R1/R2-verified): frag row m of N-tile tl holds
// original gate row g*100 + (4*tl + q), g = m&3, q = m>>2.
// => D: lane holds gates (i,f,g,o) of k=4*tl+(lane>>4), batch lane&1 in regs 0..3.
__device__ __forceinline__ int jmap(int tl, int m) { return (m & 3) * 100 + 4 * tl + (m >> 2); }

// weight element fetchers over padded K layouts (0 in pad regions).
// Bias fused at K=101 (hi) / 102 (lo) against B=1.0 — f32-exact via hi/lo f16 pair.
// L1 K-layout: [0..99]=h1, [100]=x, [101]=b_hi, [102]=b_lo, [103..127]=0
__device__ __forceinline__ __fp16 w1e(const float* Whh1, const float* Wih1,
                                      const float* bih1, const float* bhh1, int j, int k) {
  if (k < 100) return (__fp16)Whh1[j * 100 + k];
  if (k == 100) return (__fp16)Wih1[j];
  if (k == 101 || k == 102) {
    float b = bih1[j] + bhh1[j];
    __fp16 hi = (__fp16)b;
    return (k == 101) ? hi : (__fp16)(b - (float)hi);
  }
  return (__fp16)0.0f;
}
// L2 K-layout: [0..99]=h1(t), [100]=0(x-slot junk), [101]=b_hi, [102]=b_lo,
//              [103..111]=0, [112..211]=h2(t-1), [212..223]=0
__device__ __forceinline__ __fp16 w2e(const float* Wih2, const float* Whh2,
                                      const float* bih2, const float* bhh2, int j, int k) {
  if (k < 100) return (__fp16)Wih2[j * 100 + k];
  if (k == 101 || k == 102) {
    float b = bih2[j] + bhh2[j];
    __fp16 hi = (__fp16)b;
    return (k == 101) ? hi : (__fp16)(b - (float)hi);
  }
  if (k >= 112 && k < 212) return (__fp16)Whh2[j * 100 + (k - 112)];
  return (__fp16)0.0f;
}

// A-operand fragment builders: lane row m=lane&15, K elems (lane>>4)*8+0..7 of K-tile kt
__device__ __forceinline__ f16x8 mka1(const float* Whh1, const float* Wih1,
                                      const float* bih1, const float* bhh1,
                                      int tl, int kt, int m, int kg) {
  int j = jmap(tl, m);
  f16x8 r;
#pragma unroll
  for (int e = 0; e < 8; e++) r[e] = w1e(Whh1, Wih1, bih1, bhh1, j, kt * 32 + kg * 8 + e);
  return r;
}
__device__ __forceinline__ f16x8 mka2(const float* Wih2, const float* Whh2,
                                      const float* bih2, const float* bhh2,
                                      int tl, int kt, int m, int kg) {
  int j = jmap(tl, m);
  f16x8 r;
#pragma unroll
  for (int e = 0; e < 8; e++) r[e] = w2e(Wih2, Whh2, bih2, bhh2, j, kt * 32 + kg * 8 + e);
  return r;
}

__global__ __launch_bounds__(BLOCK, 2) void lstm2_mfma(
    const float* __restrict__ input,  // [512,1000]
    const float* __restrict__ Wih1,   // [400,1]
    const float* __restrict__ Whh1,   // [400,100]
    const float* __restrict__ bih1,
    const float* __restrict__ bhh1,
    const float* __restrict__ Wih2,   // [400,100]
    const float* __restrict__ Whh2,   // [400,100]
    const float* __restrict__ bih2,
    const float* __restrict__ bhh2,
    const float* __restrict__ Wlin,   // [1,100]
    const float* __restrict__ blin,   // [1]
    const int* __restrict__ futp,
    float* __restrict__ out)          // [512, 1000+future]
{
  // parity double-buffered activation vectors (B-operand sources), bank-spread rows
  __shared__ __align__(16) __fp16 H1X[2][NB][RSTR];  // h1 | x@100 | 1.0@101,102 | 0
  __shared__ __align__(16) __fp16 H2s[2][NB][RSTR];  // h2 | 0 pads
  __shared__ __align__(16) float  ybuf[2][NB][104];  // h2 f32 for TF y-dot (pads 0)
  __shared__ __align__(16) float  xrow[NB][T_IN];    // staged inputs (8 KB)
  __shared__ __align__(16) __fp16 T24[11 * 64 * 8];  // tile-24 W frags (waves 0/1, via LDS)
  __shared__ float wls[104];                         // Wlin staged (pads 0)

  const int tid = threadIdx.x;
  const int lane = tid & 63;
  const int wv = tid >> 6;
  const int b0 = blockIdx.x * NB;
  const int F = futp[0];
  const int TT = T_IN + F;

  // ---------------- init: stage + zero ----------------
  for (int i = tid; i < NB * T_IN; i += BLOCK) {
    int b = i / T_IN, tt = i % T_IN;
    xrow[b][tt] = input[(size_t)(b0 + b) * T_IN + tt];
  }
  { uint32_t* z = (uint32_t*)H1X; if (tid < 320) z[tid] = 0u; }   // 2*2*160 f16
  { uint32_t* z = (uint32_t*)H2s; if (tid < 320) z[tid] = 0u; }
  { float* z = (float*)ybuf; if (tid < 416) z[tid] = 0.0f; }      // 2*2*104 f32
  if (tid < 104) wls[tid] = (tid < HID) ? Wlin[tid] : 0.0f;

  const int n15 = lane & 15;
  const int kg = lane >> 4;         // K-chunk index 0..3
  const int bcol = lane & 1;        // batch for B-reads

  // ---- act geometry: lane activates ONE of its accumulator quads ----
  const int sel = lane & 15;
  const int cg  = sel >> 1;                       // col-group
  const int ab  = sel & 1;                        // batch
  const int aq  = lane >> 4;                      // q 0..3
  const int atl = (cg == 0) ? wv : (cg == 1) ? 8 + wv : (cg == 2) ? 16 + wv : 24;
  const int ak  = atl * 4 + aq;                   // k index this lane owns (0..99)
  const bool awr1 = (sel < 6) || (wv == 0 && sel < 8);   // L1 writers (wave0 owns tile 24)
  const bool awr2 = (sel < 6) || (wv == 1 && sel < 8);   // L2 writers (wave1 owns tile 24)
  float c1v = 0.0f, c2v = 0.0f;                   // per-lane cell states

  // ---- y duty (TF phase): wave 7 lanes 48..63 ----
  const int is_y = (tid >= 496);
  const int ybat = ((tid - 496) >> 3) & 1;
  const int yl = (tid - 496) & 7;
  const float blin0 = blin[0];

  // ---- AR-fold constants: Wlin chunks (per-lane) + Wih1 gate-quad (per-lane) ----
  f16x8 wlinv[4];
#pragma unroll
  for (int i = 0; i < 4; i++) {
#pragma unroll
    for (int e = 0; e < 8; e++) {
      int k = i * 32 + kg * 8 + e;
      wlinv[i][e] = (__fp16)((k < HID) ? Wlin[k] : 0.f);
    }
  }
  f32x4 wih1q;
#pragma unroll
  for (int g = 0; g < 4; g++) wih1q[g] = Wih1[g * 100 + ak];

  // ---- register-resident weight fragments (A-operand), tiles {wv, 8+wv, 16+wv} ----
  f16x8 W1f0[4], W1f1[4], W1f2[4], W2f0[7], W2f1[7], W2f2[7];
#pragma unroll
  for (int kt = 0; kt < 4; kt++) {
    W1f0[kt] = mka1(Whh1, Wih1, bih1, bhh1, wv, kt, n15, kg);
    W1f1[kt] = mka1(Whh1, Wih1, bih1, bhh1, 8 + wv, kt, n15, kg);
    W1f2[kt] = mka1(Whh1, Wih1, bih1, bhh1, 16 + wv, kt, n15, kg);
  }
#pragma unroll
  for (int kt = 0; kt < 7; kt++) {
    W2f0[kt] = mka2(Wih2, Whh2, bih2, bhh2, wv, kt, n15, kg);
    W2f1[kt] = mka2(Wih2, Whh2, bih2, bhh2, 8 + wv, kt, n15, kg);
    W2f2[kt] = mka2(Wih2, Whh2, bih2, bhh2, 16 + wv, kt, n15, kg);
  }
  // tile 24 fragments -> LDS (slots: 0..3 W1 kt0..3, 4..6 W2 kt4..6, 7..10 W2 kt0..3)
  if (tid < 64) {
    f16x8* TV = (f16x8*)T24;
    const int m_ = tid & 15, kg_ = tid >> 4;
#pragma unroll
    for (int kt = 0; kt < 4; kt++) TV[kt * 64 + tid] = mka1(Whh1, Wih1, bih1, bhh1, 24, kt, m_, kg_);
#pragma unroll
    for (int kt = 0; kt < 3; kt++) TV[(4 + kt) * 64 + tid] = mka2(Wih2, Whh2, bih2, bhh2, 24, 4 + kt, m_, kg_);
#pragma unroll
    for (int kt = 0; kt < 4; kt++) TV[(7 + kt) * 64 + tid] = mka2(Wih2, Whh2, bih2, bhh2, 24, kt, m_, kg_);
  }

  __syncthreads();
  // specials: bias-ones at K=101,102 (both parities/batches); x(0) into parity 1
  if (tid < 4) { H1X[tid >> 1][tid & 1][101] = (__fp16)1.0f; H1X[tid >> 1][tid & 1][102] = (__fp16)1.0f; }
  if (tid >= 4 && tid < 6) H1X[1][tid - 4][100] = (__fp16)xrow[tid - 4][0];
  __syncthreads();

  f16x8 bH1a[4], bH2[3], bl2m;
  f32x4 c0, c1, c2, c3, d0, d1, d2, d3;

// ---- B-operand reads (merged: L1 and L2 share H1X kts 0..3) ----
#define RD_H1A(P) { _Pragma("unroll") for (int kt_ = 0; kt_ < 4; kt_++) \
    bH1a[kt_] = *(const f16x8*)&H1X[P][bcol][kt_ * 32 + kg * 8]; }
#define RD_L2M(P) { f16x8 hm_ = *(const f16x8*)&H2s[P][bcol][(kg >= 2) ? ((kg - 2) * 8) : 0]; \
    bl2m = (kg >= 2) ? hm_ : bH1a[3]; }
#define RD_H2P(P) { _Pragma("unroll") for (int kt_ = 0; kt_ < 3; kt_++) \
    bH2[kt_] = *(const f16x8*)&H2s[P][bcol][16 + kt_ * 32 + kg * 8]; }

// ---- MFMA bursts (bias arrives via K=101/102) ----
#define MFMA_L1 { \
    c0 = Z4; c1 = Z4; c2 = Z4; c3 = Z4; \
    _Pragma("unroll") for (int kt_ = 0; kt_ < 4; kt_++) { \
      c0 = MF(W1f0[kt_], bH1a[kt_], c0); c1 = MF(W1f1[kt_], bH1a[kt_], c1); c2 = MF(W1f2[kt_], bH1a[kt_], c2); } \
    if (wv == 0) { const f16x8* TV = (const f16x8*)T24; \
      _Pragma("unroll") for (int kt_ = 0; kt_ < 4; kt_++) c3 = MF(TV[kt_ * 64 + lane], bH1a[kt_], c3); } }

#define MFMA_L2 { \
    d0 = Z4; d1 = Z4; d2 = Z4; d3 = Z4; \
    _Pragma("unroll") for (int kt_ = 0; kt_ < 3; kt_++) { \
      d0 = MF(W2f0[kt_], bH1a[kt_], d0); d1 = MF(W2f1[kt_], bH1a[kt_], d1); d2 = MF(W2f2[kt_], bH1a[kt_], d2); } \
    d0 = MF(W2f0[3], bl2m, d0); d1 = MF(W2f1[3], bl2m, d1); d2 = MF(W2f2[3], bl2m, d2); \
    _Pragma("unroll") for (int kt_ = 0; kt_ < 3; kt_++) { \
      d0 = MF(W2f0[kt_ + 4], bH2[kt_], d0); d1 = MF(W2f1[kt_ + 4], bH2[kt_], d1); d2 = MF(W2f2[kt_ + 4], bH2[kt_], d2); } \
    if (wv == 1) { const f16x8* TV = (const f16x8*)T24; \
      _Pragma("unroll") for (int kt_ = 0; kt_ < 3; kt_++) d3 = MF(TV[(7 + kt_) * 64 + lane], bH1a[kt_], d3); \
      d3 = MF(TV[10 * 64 + lane], bl2m, d3); \
      _Pragma("unroll") for (int kt_ = 0; kt_ < 3; kt_++) d3 = MF(TV[(4 + kt_) * 64 + lane], bH2[kt_], d3); } }

// ---- in-register activations ----
#define ACT1_TF(W_) { \
    f32x4 qq = (cg == 0) ? c0 : (cg == 1) ? c1 : (cg == 2) ? c2 : c3; \
    float sf_ = sigm(qq[1]), si_ = sigm(qq[0]), tg_ = tanh_fast(qq[2]); \
    c1v = sf_ * c1v + si_ * tg_; \
    float h_ = sigm(qq[3]) * tanh_fast(c1v); \
    if (awr1) H1X[W_][ab][ak] = (__fp16)h_; }

#define ACT1_AR(W_, YV_) { \
    f32x4 qq = (cg == 0) ? c0 : (cg == 1) ? c1 : (cg == 2) ? c2 : c3; \
    qq[0] = fmaf(wih1q[0], (YV_), qq[0]); qq[1] = fmaf(wih1q[1], (YV_), qq[1]); \
    qq[2] = fmaf(wih1q[2], (YV_), qq[2]); qq[3] = fmaf(wih1q[3], (YV_), qq[3]); \
    float sf_ = sigm(qq[1]), si_ = sigm(qq[0]), tg_ = tanh_fast(qq[2]); \
    c1v = sf_ * c1v + si_ * tg_; \
    float h_ = sigm(qq[3]) * tanh_fast(c1v); \
    if (awr1) H1X[W_][ab][ak] = (__fp16)h_; }

#define ACT2(W_, YB_) { \
    f32x4 qq = (cg == 0) ? d0 : (cg == 1) ? d1 : (cg == 2) ? d2 : d3; \
    float sf_ = sigm(qq[1]), si_ = sigm(qq[0]), tg_ = tanh_fast(qq[2]); \
    c2v = sf_ * c2v + si_ * tg_; \
    float h_ = sigm(qq[3]) * tanh_fast(c2v); \
    if (awr2) { H2s[W_][ab][ak] = (__fp16)h_; if (YB_) ybuf[W_][ab][ak] = h_; } }

#define Y_BODY(tt, RP) { \
    const float* yb_ = &ybuf[RP][ybat][0]; \
    float s = 0.0f; \
    _Pragma("unroll") \
    for (int m = 0; m < 13; m++) s = fmaf(yb_[yl + 8 * m], wls[yl + 8 * m], s); \
    s += __shfl_down(s, 4, 8); \
    s += __shfl_down(s, 2, 8); \
    s += __shfl_down(s, 1, 8); \
    if (yl == 0) out[(size_t)(b0 + ybat) * TT + (tt)] = s + blin0; }

  // ---------------- prologue: L1 gates(0) from parity 1 (zeros + x(0)) ----------------
  RD_H1A(1)
  MFMA_L1
  ACT1_TF(0)                                           // h1(0) -> H1X[0]
  if (tid >= 80 && tid < 82) H1X[0][tid - 80][100] = (__fp16)xrow[tid - 80][1];  // x(1)
  __syncthreads();

  // ====== teacher-forced fused: iter t does L2(t) + L1(t+1); ONE barrier/step ======
  for (int t = 0; t < T_IN - 1; t++) {
    const int p = t & 1, w = p ^ 1;
    RD_H1A(p) RD_L2M(p) RD_H2P(p)
    MFMA_L2
    MFMA_L1
    if (is_y && t > 0) Y_BODY(t - 1, p)                // y(t-1) off critical path
    if (tid >= 80 && tid < 82 && t + 2 < T_IN)
      H1X[w][tid - 80][100] = (__fp16)xrow[tid - 80][t + 2];  // x(t+2)
    ACT2(w, 1)                                         // h2(t)
    ACT1_TF(w)                                         // h1(t+1)
    __syncthreads();
  }

  // ---- one-time AR patch: remove x-coefficient from L1 kt3 (x-slot is stale in AR) ----
  if (kg == 0) {
    W1f0[3][4] = (__fp16)0.f; W1f1[3][4] = (__fp16)0.f; W1f2[3][4] = (__fp16)0.f;
  }
  if (tid < 16) ((__fp16*)T24)[3 * 512 + tid * 8 + 4] = (__fp16)0.f;  // slot3 kg0 elem4
  __syncthreads();

  // ====== autoregressive: 2 barriers/step; y folded as rank-1 scalar (s = Wlin.h2) ======
  for (int t = T_IN - 1; t < TT; t++) {
    const int p = t & 1, w = p ^ 1;
    RD_H1A(p) RD_L2M(p) RD_H2P(p)
    MFMA_L2                                            // gates2(t)
    MFMA_L1                                            // L1(t+1) recurrent part (h1(t) only)
    if (is_y && t == T_IN - 1) Y_BODY(t - 1, p)        // catch-up y(T_IN-2)
    ACT2(w, 0)                                         // h2(t)
    __syncthreads();                                   // B1: h2(t) visible
    float s_ = 0.f;
#pragma unroll
    for (int i_ = 0; i_ < 4; i_++) {                   // s = Wlin . h2(t)  (per-lane batch)
      f16x8 hh_ = *(const f16x8*)&H2s[w][bcol][i_ * 32 + kg * 8];
      s_ = dot8(hh_, wlinv[i_], s_);
    }
    s_ += __shfl_xor(s_, 16, 64);
    s_ += __shfl_xor(s_, 32, 64);
    const float yv = s_ + blin0;                       // y(t) = x(t+1)
    if (wv == 0 && lane < 2) out[(size_t)(b0 + lane) * TT + t] = yv;
    ACT1_AR(w, yv)                                     // h1(t+1), x-term added in-register
    __syncthreads();                                   // B2: h1(t+1) visible
  }
}

extern "C" void kernel_launch(void* const* d_in, const int* in_sizes, int n_in,
                              void* d_out, int out_size, void* d_ws, size_t ws_size,
                              hipStream_t stream) {
  const float* input = (const float*)d_in[0];
  const float* Wih1  = (const float*)d_in[1];
  const float* Whh1  = (const float*)d_in[2];
  const float* bih1  = (const float*)d_in[3];
  const float* bhh1  = (const float*)d_in[4];
  const float* Wih2  = (const float*)d_in[5];
  const float* Whh2  = (const float*)d_in[6];
  const float* bih2  = (const float*)d_in[7];
  const float* bhh2  = (const float*)d_in[8];
  const float* Wlin  = (const float*)d_in[9];
  const float* blin  = (const float*)d_in[10];
  const int*   futp  = (const int*)d_in[11];
  float* out = (float*)d_out;

  dim3 grid(B_TOTAL / NB);  // 256 blocks, 1 per CU
  dim3 block(BLOCK);
  hipLaunchKernelGGL(lstm2_mfma, grid, block, 0, stream,
                     input, Wih1, Whh1, bih1, bhh1, Wih2, Whh2, bih2, bhh2,
                     Wlin, blin, futp, out);
}